// Round 6
// baseline (320.666 us; speedup 1.0000x reference)
//
#include <hip/hip_runtime.h>
#include <stdint.h>

// ---------------------------------------------------------------------------
// EncoderBlock: LN1 -> QKV GEMM -> MHA (flash) -> +resid -> LN2 -> FFN(GELU)
// bf16 MFMA (16x16x32), fp32 accumulate. S=4096, D=1024, H=8, hd=128, FF=4096.
// R5: attn = 64 q rows/wave (4 Q-sets), kf deduped (nf-outer/kk-inner, one
//     kf read feeds 4 MFMA chains), per-nf softmax+P-write; KV-split x4 with
//     bf16 O partials. LDS bytes/FLOP cut ~2.3x vs R4 (LDS-issue-bound fix).
// ---------------------------------------------------------------------------

typedef __bf16 bf16;
typedef __attribute__((ext_vector_type(8))) __bf16 bf16x8;
typedef __attribute__((ext_vector_type(4))) __bf16 bf16x4;
typedef __attribute__((ext_vector_type(4))) float f32x4;

#define DEV static __device__ __forceinline__

// Q pre-scale folded at QKV epilogue: (1/sqrt(128)) * log2(e)
#define QSCALE 0.12751741687f

DEV void gload_lds16(const void* gsrc, void* ldst) {
  typedef const __attribute__((address_space(1))) uint32_t gq_t;
  typedef __attribute__((address_space(3))) uint32_t lq_t;
  __builtin_amdgcn_global_load_lds((gq_t*)(uintptr_t)gsrc, (lq_t*)(uintptr_t)ldst,
                                   16, 0, 0);
}

DEV f32x4 mfma16(bf16x8 a, bf16x8 b, f32x4 c) {
  return __builtin_amdgcn_mfma_f32_16x16x32_bf16(a, b, c, 0, 0, 0);
}

// ---------------------------------------------------------------------------
// LN1: x fp32 [4096,1024] -> bf16 h. One block per row.
// ---------------------------------------------------------------------------
__global__ __launch_bounds__(256) void ln1_kernel(
    const float* __restrict__ x, const float* __restrict__ gw,
    const float* __restrict__ bw, bf16* __restrict__ out) {
  int row = blockIdx.x, t = threadIdx.x;
  const float* xr = x + (size_t)row * 1024;
  f32x4 v = *(const f32x4*)(xr + t * 4);
  float s = v[0] + v[1] + v[2] + v[3];
  float s2 = v[0] * v[0] + v[1] * v[1] + v[2] * v[2] + v[3] * v[3];
#pragma unroll
  for (int off = 1; off < 64; off <<= 1) {
    s += __shfl_xor(s, off);
    s2 += __shfl_xor(s2, off);
  }
  __shared__ float red[8];
  if ((t & 63) == 0) { red[t >> 6] = s; red[4 + (t >> 6)] = s2; }
  __syncthreads();
  s = red[0] + red[1] + red[2] + red[3];
  s2 = red[4] + red[5] + red[6] + red[7];
  float mu = s * (1.f / 1024.f);
  float rstd = rsqrtf(s2 * (1.f / 1024.f) - mu * mu + 1e-5f);
  f32x4 gv = *(const f32x4*)(gw + t * 4);
  f32x4 bv = *(const f32x4*)(bw + t * 4);
  bf16x4 o;
#pragma unroll
  for (int j = 0; j < 4; j++) o[j] = (bf16)((v[j] - mu) * rstd * gv[j] + bv[j]);
  *(bf16x4*)(out + (size_t)row * 1024 + t * 4) = o;
}

// ---------------------------------------------------------------------------
// combine + resid + LN2: o = (sum_z O_z)/(sum_z l_z); h2 = LN(o + h)
// O partials are bf16, 4 kv-splits.
// ---------------------------------------------------------------------------
__global__ __launch_bounds__(256) void resid_ln2_kernel(
    const bf16* __restrict__ Op, const float* __restrict__ lbuf,
    const bf16* __restrict__ h, const float* __restrict__ gw,
    const float* __restrict__ bw, bf16* __restrict__ out) {
  int row = blockIdx.x, t = threadIdx.x;
  int head = t >> 5;  // 32 threads (128 cols) per head
  float l = 0.f;
  float acc[4] = {0.f, 0.f, 0.f, 0.f};
#pragma unroll
  for (int z = 0; z < 4; z++) {
    l += lbuf[(size_t)(z * 8 + head) * 4096 + row];
    bf16x4 ov = *(const bf16x4*)(Op + (size_t)z * 4096 * 1024 +
                                 (size_t)row * 1024 + t * 4);
#pragma unroll
    for (int j = 0; j < 4; j++) acc[j] += (float)ov[j];
  }
  float rl = 1.0f / l;
  bf16x4 hv = *(const bf16x4*)(h + (size_t)row * 1024 + t * 4);
  float vv[4];
#pragma unroll
  for (int j = 0; j < 4; j++) vv[j] = acc[j] * rl + (float)hv[j];
  float s = vv[0] + vv[1] + vv[2] + vv[3];
  float s2 = vv[0] * vv[0] + vv[1] * vv[1] + vv[2] * vv[2] + vv[3] * vv[3];
#pragma unroll
  for (int off = 1; off < 64; off <<= 1) {
    s += __shfl_xor(s, off);
    s2 += __shfl_xor(s2, off);
  }
  __shared__ float red[8];
  if ((t & 63) == 0) { red[t >> 6] = s; red[4 + (t >> 6)] = s2; }
  __syncthreads();
  s = red[0] + red[1] + red[2] + red[3];
  s2 = red[4] + red[5] + red[6] + red[7];
  float mu = s * (1.f / 1024.f);
  float rstd = rsqrtf(s2 * (1.f / 1024.f) - mu * mu + 1e-5f);
  f32x4 gv = *(const f32x4*)(gw + t * 4);
  f32x4 bv = *(const f32x4*)(bw + t * 4);
  bf16x4 o;
#pragma unroll
  for (int j = 0; j < 4; j++) o[j] = (bf16)((vv[j] - mu) * rstd * gv[j] + bv[j]);
  *(bf16x4*)(out + (size_t)row * 1024 + t * 4) = o;
}

// ---------------------------------------------------------------------------
// transpose+cast: in fp32 [R][C] -> out bf16 [C][R]. R,C multiples of 32.
// ---------------------------------------------------------------------------
__global__ __launch_bounds__(256) void transpose_f32_bf16(
    const float* __restrict__ in, bf16* __restrict__ out, int R, int C) {
  __shared__ float tile[32][33];
  int c0 = blockIdx.x * 32, r0 = blockIdx.y * 32;
  int tx = threadIdx.x & 31, ty = threadIdx.x >> 5;
#pragma unroll
  for (int j = 0; j < 4; j++)
    tile[ty + 8 * j][tx] = in[(size_t)(r0 + ty + 8 * j) * C + c0 + tx];
  __syncthreads();
#pragma unroll
  for (int j = 0; j < 4; j++)
    out[(size_t)(c0 + ty + 8 * j) * R + r0 + tx] = (bf16)tile[tx][ty + 8 * j];
}

// V transpose: vt[c][s] = qkv[s][2048+c], c<1024, s<4096 (bf16 -> bf16)
__global__ __launch_bounds__(256) void transpose_v_kernel(
    const bf16* __restrict__ qkv, bf16* __restrict__ vt) {
  __shared__ bf16 tile[32][33];
  int c0 = blockIdx.x * 32, s0 = blockIdx.y * 32;
  int tx = threadIdx.x & 31, ty = threadIdx.x >> 5;
#pragma unroll
  for (int j = 0; j < 4; j++)
    tile[ty + 8 * j][tx] = qkv[(size_t)(s0 + ty + 8 * j) * 3072 + 2048 + c0 + tx];
  __syncthreads();
#pragma unroll
  for (int j = 0; j < 4; j++)
    vt[(size_t)(c0 + ty + 8 * j) * 4096 + s0 + tx] = tile[tx][ty + 8 * j];
}

// ---------------------------------------------------------------------------
// GEMM: C[M,N] = A[M,K](bf16) @ Bt[N,K](bf16)^T + bias. Tile BM x 128, BK=64.
// T1 XCD-chunked block swizzle (grid size must be %8==0).
// EPILOG: 0 bf16 | 1 GELU(tanh-approx)+bf16 | 2 fp32 | 3 bf16, Q-scale col<1024
// ---------------------------------------------------------------------------
template <int EPILOG, int BM>
__global__ __launch_bounds__(256) void gemm_bt_kernel(
    const bf16* __restrict__ A, const bf16* __restrict__ Bt,
    const float* __restrict__ bias, void* __restrict__ Cout,
    int M, int N, int K) {
  constexpr int MR = BM / 32;  // m-fragments per wave
  __shared__ bf16 sA[BM * 64];
  __shared__ bf16 sB[128 * 64];
  // T1: contiguous chunk of blocks per XCD
  int nwg = gridDim.x * gridDim.y;
  int bid = blockIdx.y * gridDim.x + blockIdx.x;
  int swz = (bid & 7) * (nwg >> 3) + (bid >> 3);
  int bx = swz % gridDim.x, by = swz / gridDim.x;
  int m0 = by * BM, n0 = bx * 128;
  int tid = threadIdx.x;
  int wave = tid >> 6, lane = tid & 63;
  int lr = lane & 15, lg = lane >> 4;
  int wr = (wave >> 1) * (BM / 2), wc = (wave & 1) * 64;

  f32x4 acc[MR][4] = {};

  int srow = tid >> 3;          // 0..31
  int scol = (tid & 7) * 8;     // element col within 64-wide K chunk
  const bf16* Abase = A + (size_t)(m0 + srow) * K + scol;
  const bf16* Bbase = Bt + (size_t)(n0 + srow) * K + scol;

  for (int kt = 0; kt < K; kt += 64) {
#pragma unroll
    for (int i = 0; i < BM / 32; i++)
      gload_lds16(Abase + (size_t)(i * 32) * K + kt,
                  (char*)sA + i * 4096 + wave * 1024);
#pragma unroll
    for (int i = 0; i < 4; i++)
      gload_lds16(Bbase + (size_t)(i * 32) * K + kt,
                  (char*)sB + i * 4096 + wave * 1024);
    __syncthreads();
    bf16x8 af[MR][2], bfv[4][2];
#pragma unroll
    for (int m = 0; m < MR; m++)
#pragma unroll
      for (int kk = 0; kk < 2; kk++)
        af[m][kk] = *(const bf16x8*)&sA[(wr + m * 16 + lr) * 64 + kk * 32 + lg * 8];
#pragma unroll
    for (int n = 0; n < 4; n++)
#pragma unroll
      for (int kk = 0; kk < 2; kk++)
        bfv[n][kk] = *(const bf16x8*)&sB[(wc + n * 16 + lr) * 64 + kk * 32 + lg * 8];
#pragma unroll
    for (int kk = 0; kk < 2; kk++)
#pragma unroll
      for (int m = 0; m < MR; m++)
#pragma unroll
        for (int n = 0; n < 4; n++)
          acc[m][n] = mfma16(af[m][kk], bfv[n][kk], acc[m][n]);
    __syncthreads();
  }

#pragma unroll
  for (int n = 0; n < 4; n++) {
    int col = n0 + wc + n * 16 + lr;
    float bs = bias[col];
#pragma unroll
    for (int m = 0; m < MR; m++) {
#pragma unroll
      for (int r = 0; r < 4; r++) {
        int row = m0 + wr + m * 16 + lg * 4 + r;
        float v = acc[m][n][r] + bs;
        if constexpr (EPILOG == 1) {
          // sigmoid-form tanh GELU: x * sigmoid(2*0.79788456*(x+0.044715x^3))
          float u = v + 0.044715f * v * v * v;
          float e = __builtin_amdgcn_exp2f(-2.3021144f * u);
          v = v / (1.0f + e);
        }
        if constexpr (EPILOG == 3) { if (col < 1024) v *= QSCALE; }
        if constexpr (EPILOG == 2)
          ((float*)Cout)[(size_t)row * N + col] = v;
        else
          ((bf16*)Cout)[(size_t)row * N + col] = (bf16)v;
      }
    }
  }
}

// ---------------------------------------------------------------------------
// Flash attention, KV-split x4, 64 q rows per wave (QBLK=256 per block).
// grid (16 qtiles, 8 heads, 4 kv-quarters), 256 thr, 64KB LDS (2 blocks/CU).
// Per KV-tile: kf reads deduped across ALL 4 q-sets (nf outer, kk inner, one
// kf read feeds 4 independent MFMA chains); vf shared across q-sets.
// LDS ops per wave-tile: 16 kf + 16 vf + 8 pa reads + 16 b64 writes for
// 128 MFMAs (0.31 reads/MFMA vs R4's 0.94) -- attacks the LDS-issue bound.
// Static max (m=0, exp2 units, |s|<~8); l deferred to epilogue; O partials
// written UNNORMALIZED in bf16. S^T = K @ Q^T swapped MFMA.
// All LDS tiles XOR-swizzled both-sides (rule 21).
// ---------------------------------------------------------------------------
__global__ __launch_bounds__(256) void attn_kernel(
    const bf16* __restrict__ qkv, const bf16* __restrict__ vt,
    bf16* __restrict__ opart, float* __restrict__ lbuf) {
  constexpr int S = 4096, C3 = 3072;
  __shared__ bf16 sK[64 * 128];       // 16KB
  __shared__ bf16 sV[128 * 64];       // 16KB
  __shared__ bf16 sP[4 * 64 * 64];    // 32KB, 8KB per wave
  int hh = blockIdx.y;
  int q0 = blockIdx.x * 256;
  int z = blockIdx.z;
  int kv_begin = z * (S / 4), kv_end = kv_begin + (S / 4);
  bf16* obuf = opart + (size_t)z * 4096 * 1024;
  int tid = threadIdx.x, wave = tid >> 6, lane = tid & 63;
  int lr = lane & 15, lg = lane >> 4;

  // Q fragments: 4 sets of 16 q rows (rows q0 + wave*64 + qs*16 + lr)
  bf16x8 qf[4][4];
#pragma unroll
  for (int qs = 0; qs < 4; qs++) {
    const bf16* qrow =
        qkv + (size_t)(q0 + wave * 64 + qs * 16 + lr) * C3 + hh * 128 + lg * 8;
#pragma unroll
    for (int kk = 0; kk < 4; kk++) qf[qs][kk] = *(const bf16x8*)(qrow + kk * 32);
  }
  f32x4 o[4][8] = {};
  float lsum[4] = {0.f, 0.f, 0.f, 0.f};

  const int krow_s = tid >> 4;                          // +16*i
  const int kcb = (tid & 15) * 16;
  const int scbK = kcb ^ ((krow_s & 7) << 4);           // i*16 preserves &7
  const int vrow_s = tid >> 3;                          // +32*i
  const int vcb = (tid & 7) * 16;
  const int scbV = vcb ^ ((vrow_s & 7) << 4);

  const bf16* kbase = qkv + 1024 + hh * 128 + scbK / 2;
  const bf16* vbase = vt + (size_t)(hh * 128 + vrow_s) * S + scbV / 2;

  for (int kv0 = kv_begin; kv0 < kv_end; kv0 += 64) {
#pragma unroll
    for (int i = 0; i < 4; i++)
      gload_lds16(kbase + (size_t)(kv0 + i * 16 + krow_s) * C3,
                  (char*)sK + i * 4096 + wave * 1024);
#pragma unroll
    for (int i = 0; i < 4; i++)
      gload_lds16(vbase + (size_t)(i * 32) * S + kv0,
                  (char*)sV + i * 4096 + wave * 1024);
    __syncthreads();

    char* pw = (char*)sP + wave * 8192;

    // QK: S^T = K @ Q^T. nf outer, kk inner; ONE kf read feeds 4 q-set MFMAs
    // (4 independent accumulation chains = free MFMA ILP).
#pragma unroll
    for (int nf = 0; nf < 4; nf++) {
      f32x4 sc0 = {0.f, 0.f, 0.f, 0.f}, sc1 = sc0, sc2 = sc0, sc3 = sc0;
      __builtin_amdgcn_s_setprio(1);
#pragma unroll
      for (int kk = 0; kk < 4; kk++) {
        int krow = nf * 16 + lr;
        int db = (kk * 64 + lg * 16) ^ ((krow & 7) << 4);
        bf16x8 kf = *(const bf16x8*)((const char*)sK + krow * 256 + db);
        sc0 = mfma16(kf, qf[0][kk], sc0);
        sc1 = mfma16(kf, qf[1][kk], sc1);
        sc2 = mfma16(kf, qf[2][kk], sc2);
        sc3 = mfma16(kf, qf[3][kk], sc3);
      }
      __builtin_amdgcn_s_setprio(0);
      // P = exp2(S); local l accum; write P rows (8B ds_write, swizzled)
      f32x4 scs[4] = {sc0, sc1, sc2, sc3};
#pragma unroll
      for (int qs = 0; qs < 4; qs++) {
        float p0 = __builtin_amdgcn_exp2f(scs[qs][0]);
        float p1 = __builtin_amdgcn_exp2f(scs[qs][1]);
        float p2 = __builtin_amdgcn_exp2f(scs[qs][2]);
        float p3 = __builtin_amdgcn_exp2f(scs[qs][3]);
        lsum[qs] += (p0 + p1) + (p2 + p3);
        bf16x4 pk;
        pk[0] = (bf16)p0; pk[1] = (bf16)p1; pk[2] = (bf16)p2; pk[3] = (bf16)p3;
        *(bf16x4*)(pw + (qs * 16 + lr) * 128 +
                   ((nf * 32 + lg * 8) ^ ((lr & 7) << 4))) = pk;
      }
    }

    // PV: O[64 q][128 d] += P @ V ; vf reads shared across all 4 q-sets
#pragma unroll
    for (int kk = 0; kk < 2; kk++) {
      int dbp = (kk * 64 + lg * 16) ^ ((lr & 7) << 4);
      bf16x8 pa0 = *(const bf16x8*)(pw + (0 * 16 + lr) * 128 + dbp);
      bf16x8 pa1 = *(const bf16x8*)(pw + (1 * 16 + lr) * 128 + dbp);
      bf16x8 pa2 = *(const bf16x8*)(pw + (2 * 16 + lr) * 128 + dbp);
      bf16x8 pa3 = *(const bf16x8*)(pw + (3 * 16 + lr) * 128 + dbp);
      __builtin_amdgcn_s_setprio(1);
#pragma unroll
      for (int df = 0; df < 8; df++) {
        int vrow = df * 16 + lr;
        int db = (kk * 64 + lg * 16) ^ ((vrow & 7) << 4);
        bf16x8 vf = *(const bf16x8*)((const char*)sV + vrow * 128 + db);
        o[0][df] = mfma16(pa0, vf, o[0][df]);
        o[1][df] = mfma16(pa1, vf, o[1][df]);
        o[2][df] = mfma16(pa2, vf, o[2][df]);
        o[3][df] = mfma16(pa3, vf, o[3][df]);
      }
      __builtin_amdgcn_s_setprio(0);
    }
    __syncthreads();
  }

  // epilogue: finish l partials, write l + unnormalized bf16 O
#pragma unroll
  for (int qs = 0; qs < 4; qs++) {
    float ls = lsum[qs];
    ls += __shfl_xor(ls, 16);
    ls += __shfl_xor(ls, 32);   // lane (lr, *) has l-partial for its q
    if (lg == 0)
      lbuf[(size_t)(z * 8 + hh) * 4096 + q0 + wave * 64 + qs * 16 + lr] = ls;
#pragma unroll
    for (int df = 0; df < 8; df++) {
      int col = hh * 128 + df * 16 + lr;
#pragma unroll
      for (int r = 0; r < 4; r++) {
        int row = q0 + wave * 64 + qs * 16 + lg * 4 + r;
        obuf[(size_t)row * 1024 + col] = (bf16)o[qs][df][r];
      }
    }
  }
}

// ---------------------------------------------------------------------------
// Launch. Workspace layout (peak 78.5 MB), liveness-ordered reuse:
//   [0,8M)        h bf16        (ln1 -> resid_ln2)
//   [8,32M)       qkv bf16      (gemmQKV -> attn); after attn:
//     [8,16M)     h2 bf16       (resid_ln2 -> ffn1)
//     [16,24M)    w1T bf16      (transpose -> ffn1)
//     [24,32M)    w2T bf16      (transpose -> ffn2)
//   [32,40M)      vt bf16       (transpose_v -> attn)
//   [40,72M)      O partials bf16 x4 (attn -> resid_ln2); then ffn1 bf16 32MB
//   [72M,+512K)   l fp32 [4][8][4096]
//   [72.5,78.5M)  qkv_wT bf16 6MB
// ---------------------------------------------------------------------------
extern "C" void kernel_launch(void* const* d_in, const int* in_sizes, int n_in,
                              void* d_out, int out_size, void* d_ws, size_t ws_size,
                              hipStream_t stream) {
  const float* x     = (const float*)d_in[0];
  const float* ln1_g = (const float*)d_in[1];
  const float* ln1_b = (const float*)d_in[2];
  const float* qkv_w = (const float*)d_in[3];
  const float* qkv_b = (const float*)d_in[4];
  const float* ln2_g = (const float*)d_in[5];
  const float* ln2_b = (const float*)d_in[6];
  const float* w1    = (const float*)d_in[7];
  const float* b1    = (const float*)d_in[8];
  const float* w2    = (const float*)d_in[9];
  const float* b2    = (const float*)d_in[10];

  char* ws = (char*)d_ws;
  const size_t MB = 1ull << 20;
  bf16*  h    = (bf16*)(ws + 0);
  bf16*  qkv  = (bf16*)(ws + 8 * MB);
  bf16*  h2   = (bf16*)(ws + 8 * MB);    // alias: qkv dead after attn
  bf16*  w1T  = (bf16*)(ws + 16 * MB);   // alias: qkv dead after attn
  bf16*  w2T  = (bf16*)(ws + 24 * MB);   // alias: qkv dead after attn
  bf16*  vt   = (bf16*)(ws + 32 * MB);
  bf16*  Op   = (bf16*)(ws + 40 * MB);   // 4 x 8MB bf16 partials
  bf16*  ffn1 = (bf16*)(ws + 40 * MB);   // alias: O dead after resid_ln2
  float* lbuf = (float*)(ws + 72 * MB);
  bf16*  wTq  = (bf16*)(ws + 72 * MB + 512 * 1024);
  float* outp = (float*)d_out;

  // 1. LN1
  ln1_kernel<<<4096, 256, 0, stream>>>(x, ln1_g, ln1_b, h);
  // 2. qkv_w [1024,3072] -> wTq [3072,1024]
  transpose_f32_bf16<<<dim3(3072 / 32, 1024 / 32), 256, 0, stream>>>(qkv_w, wTq, 1024, 3072);
  // 3. qkv = h @ qkv_w + b (Q cols pre-scaled)  [4096,3072] bf16
  gemm_bt_kernel<3, 128><<<dim3(3072 / 128, 4096 / 128), 256, 0, stream>>>(
      h, wTq, qkv_b, qkv, 4096, 3072, 1024);
  // 4. vt[c][s] = v
  transpose_v_kernel<<<dim3(1024 / 32, 4096 / 32), 256, 0, stream>>>(qkv, vt);
  // 5. attention, KV-split x4, QBLK=256 -> unnormalized bf16 O partials + l
  attn_kernel<<<dim3(16, 8, 4), 256, 0, stream>>>(qkv, vt, Op, lbuf);
  // 6. w1 [1024,4096] -> w1T [4096,1024]   (after attn: overwrites qkv region)
  transpose_f32_bf16<<<dim3(4096 / 32, 1024 / 32), 256, 0, stream>>>(w1, w1T, 1024, 4096);
  // 7. w2 [4096,1024] -> w2T [1024,4096]
  transpose_f32_bf16<<<dim3(1024 / 32, 4096 / 32), 256, 0, stream>>>(w2, w2T, 4096, 1024);
  // 8. h2 = LN2((sum_z O_z)/(sum_z l_z) + h)
  resid_ln2_kernel<<<4096, 256, 0, stream>>>(Op, lbuf, h, ln2_g, ln2_b, h2);
  // 9. ffn1 = gelu(h2 @ w1 + b1)  [4096,4096] bf16
  gemm_bt_kernel<1, 128><<<dim3(4096 / 128, 4096 / 128), 256, 0, stream>>>(
      h2, w1T, b1, ffn1, 4096, 4096, 1024);
  // 10. out = ffn1 @ w2 + b2  fp32 (BM=64: 512 blocks, 2/CU)
  gemm_bt_kernel<2, 64><<<dim3(1024 / 128, 4096 / 64), 256, 0, stream>>>(
      ffn1, w2T, b2, outp, 4096, 1024, 4096);
}

// Round 7
// 276.373 us; speedup vs baseline: 1.1603x; 1.1603x over previous
//
#include <hip/hip_runtime.h>
#include <stdint.h>

// ---------------------------------------------------------------------------
// EncoderBlock: LN1 -> QKV GEMM -> MHA (flash) -> +resid -> LN2 -> FFN(GELU)
// bf16 MFMA (16x16x32), fp32 accumulate. S=4096, D=1024, H=8, hd=128, FF=4096.
// R6: attn = R5 structure (best: 95.6us) + kf-dedup (nf-outer, one kf read
//     feeds both q-sets) at unchanged 48KB/occupancy. QKV+FFN1 GEMMs move to
//     8-wave 256x128 tiles; V-transpose fused into QKV epilogue.
// ---------------------------------------------------------------------------

typedef __bf16 bf16;
typedef __attribute__((ext_vector_type(8))) __bf16 bf16x8;
typedef __attribute__((ext_vector_type(4))) __bf16 bf16x4;
typedef __attribute__((ext_vector_type(4))) float f32x4;

#define DEV static __device__ __forceinline__

// Q pre-scale folded at QKV epilogue: (1/sqrt(128)) * log2(e)
#define QSCALE 0.12751741687f

DEV void gload_lds16(const void* gsrc, void* ldst) {
  typedef const __attribute__((address_space(1))) uint32_t gq_t;
  typedef __attribute__((address_space(3))) uint32_t lq_t;
  __builtin_amdgcn_global_load_lds((gq_t*)(uintptr_t)gsrc, (lq_t*)(uintptr_t)ldst,
                                   16, 0, 0);
}

DEV f32x4 mfma16(bf16x8 a, bf16x8 b, f32x4 c) {
  return __builtin_amdgcn_mfma_f32_16x16x32_bf16(a, b, c, 0, 0, 0);
}

// ---------------------------------------------------------------------------
// LN1: x fp32 [4096,1024] -> bf16 h. One block per row.
// ---------------------------------------------------------------------------
__global__ __launch_bounds__(256) void ln1_kernel(
    const float* __restrict__ x, const float* __restrict__ gw,
    const float* __restrict__ bw, bf16* __restrict__ out) {
  int row = blockIdx.x, t = threadIdx.x;
  const float* xr = x + (size_t)row * 1024;
  f32x4 v = *(const f32x4*)(xr + t * 4);
  float s = v[0] + v[1] + v[2] + v[3];
  float s2 = v[0] * v[0] + v[1] * v[1] + v[2] * v[2] + v[3] * v[3];
#pragma unroll
  for (int off = 1; off < 64; off <<= 1) {
    s += __shfl_xor(s, off);
    s2 += __shfl_xor(s2, off);
  }
  __shared__ float red[8];
  if ((t & 63) == 0) { red[t >> 6] = s; red[4 + (t >> 6)] = s2; }
  __syncthreads();
  s = red[0] + red[1] + red[2] + red[3];
  s2 = red[4] + red[5] + red[6] + red[7];
  float mu = s * (1.f / 1024.f);
  float rstd = rsqrtf(s2 * (1.f / 1024.f) - mu * mu + 1e-5f);
  f32x4 gv = *(const f32x4*)(gw + t * 4);
  f32x4 bv = *(const f32x4*)(bw + t * 4);
  bf16x4 o;
#pragma unroll
  for (int j = 0; j < 4; j++) o[j] = (bf16)((v[j] - mu) * rstd * gv[j] + bv[j]);
  *(bf16x4*)(out + (size_t)row * 1024 + t * 4) = o;
}

// ---------------------------------------------------------------------------
// combine + resid + LN2: o = (O0+O1)/(l0+l1); h2 = LN(o + h)
// ---------------------------------------------------------------------------
__global__ __launch_bounds__(256) void resid_ln2_kernel(
    const float* __restrict__ O0, const float* __restrict__ O1,
    const float* __restrict__ lbuf, const bf16* __restrict__ h,
    const float* __restrict__ gw, const float* __restrict__ bw,
    bf16* __restrict__ out) {
  int row = blockIdx.x, t = threadIdx.x;
  int head = t >> 5;  // 32 threads (128 cols) per head
  float l = lbuf[head * 4096 + row] + lbuf[(8 + head) * 4096 + row];
  float rl = 1.0f / l;
  f32x4 a0 = *(const f32x4*)(O0 + (size_t)row * 1024 + t * 4);
  f32x4 a1 = *(const f32x4*)(O1 + (size_t)row * 1024 + t * 4);
  bf16x4 hv = *(const bf16x4*)(h + (size_t)row * 1024 + t * 4);
  float vv[4];
#pragma unroll
  for (int j = 0; j < 4; j++) vv[j] = (a0[j] + a1[j]) * rl + (float)hv[j];
  float s = vv[0] + vv[1] + vv[2] + vv[3];
  float s2 = vv[0] * vv[0] + vv[1] * vv[1] + vv[2] * vv[2] + vv[3] * vv[3];
#pragma unroll
  for (int off = 1; off < 64; off <<= 1) {
    s += __shfl_xor(s, off);
    s2 += __shfl_xor(s2, off);
  }
  __shared__ float red[8];
  if ((t & 63) == 0) { red[t >> 6] = s; red[4 + (t >> 6)] = s2; }
  __syncthreads();
  s = red[0] + red[1] + red[2] + red[3];
  s2 = red[4] + red[5] + red[6] + red[7];
  float mu = s * (1.f / 1024.f);
  float rstd = rsqrtf(s2 * (1.f / 1024.f) - mu * mu + 1e-5f);
  f32x4 gv = *(const f32x4*)(gw + t * 4);
  f32x4 bv = *(const f32x4*)(bw + t * 4);
  bf16x4 o;
#pragma unroll
  for (int j = 0; j < 4; j++) o[j] = (bf16)((vv[j] - mu) * rstd * gv[j] + bv[j]);
  *(bf16x4*)(out + (size_t)row * 1024 + t * 4) = o;
}

// ---------------------------------------------------------------------------
// transpose+cast: in fp32 [R][C] -> out bf16 [C][R]. R,C multiples of 32.
// ---------------------------------------------------------------------------
__global__ __launch_bounds__(256) void transpose_f32_bf16(
    const float* __restrict__ in, bf16* __restrict__ out, int R, int C) {
  __shared__ float tile[32][33];
  int c0 = blockIdx.x * 32, r0 = blockIdx.y * 32;
  int tx = threadIdx.x & 31, ty = threadIdx.x >> 5;
#pragma unroll
  for (int j = 0; j < 4; j++)
    tile[ty + 8 * j][tx] = in[(size_t)(r0 + ty + 8 * j) * C + c0 + tx];
  __syncthreads();
#pragma unroll
  for (int j = 0; j < 4; j++)
    out[(size_t)(c0 + ty + 8 * j) * R + r0 + tx] = (bf16)tile[tx][ty + 8 * j];
}

// ---------------------------------------------------------------------------
// 8-wave GEMM: C[M,N] = A[M,K] @ Bt[N,K]^T + bias. Tile 256x128, BK=64,
// 512 threads (8 waves = 4M x 2N, each wave 64x64). T1 XCD swizzle.
// EPILOG: 1 = GELU(tanh)+bf16 | 3 = QKV: Q-scale col<1024, V cols>=2048
//         written TRANSPOSED to Vout[col-2048][row] (bf16x4 row-runs).
// ---------------------------------------------------------------------------
template <int EPILOG>
__global__ __launch_bounds__(512) void gemm8_kernel(
    const bf16* __restrict__ A, const bf16* __restrict__ Bt,
    const float* __restrict__ bias, bf16* __restrict__ Cout,
    bf16* __restrict__ Vout, int M, int N, int K) {
  __shared__ bf16 sA[256 * 64];   // 32KB
  __shared__ bf16 sB[128 * 64];   // 16KB
  int nwg = gridDim.x * gridDim.y;
  int bid = blockIdx.y * gridDim.x + blockIdx.x;
  int swz = (bid & 7) * (nwg >> 3) + (bid >> 3);
  int bx = swz % gridDim.x, by = swz / gridDim.x;
  int m0 = by * 256, n0 = bx * 128;
  int tid = threadIdx.x;
  int wave = tid >> 6, lane = tid & 63;
  int lr = lane & 15, lg = lane >> 4;
  int wr = (wave >> 1) * 64, wc = (wave & 1) * 64;

  f32x4 acc[4][4] = {};

  int srow = tid >> 3;          // 0..63 (64 rows per staging pass)
  int scol = (tid & 7) * 8;
  const bf16* Abase = A + (size_t)(m0 + srow) * K + scol;
  const bf16* Bbase = Bt + (size_t)(n0 + srow) * K + scol;

  for (int kt = 0; kt < K; kt += 64) {
#pragma unroll
    for (int i = 0; i < 4; i++)   // A: 256 rows = 4 x 64
      gload_lds16(Abase + (size_t)(i * 64) * K + kt,
                  (char*)sA + i * 8192 + wave * 1024);
#pragma unroll
    for (int i = 0; i < 2; i++)   // B: 128 rows = 2 x 64
      gload_lds16(Bbase + (size_t)(i * 64) * K + kt,
                  (char*)sB + i * 8192 + wave * 1024);
    __syncthreads();
    bf16x8 af[4][2], bfv[4][2];
#pragma unroll
    for (int m = 0; m < 4; m++)
#pragma unroll
      for (int kk = 0; kk < 2; kk++)
        af[m][kk] = *(const bf16x8*)&sA[(wr + m * 16 + lr) * 64 + kk * 32 + lg * 8];
#pragma unroll
    for (int n = 0; n < 4; n++)
#pragma unroll
      for (int kk = 0; kk < 2; kk++)
        bfv[n][kk] = *(const bf16x8*)&sB[(wc + n * 16 + lr) * 64 + kk * 32 + lg * 8];
#pragma unroll
    for (int kk = 0; kk < 2; kk++)
#pragma unroll
      for (int m = 0; m < 4; m++)
#pragma unroll
        for (int n = 0; n < 4; n++)
          acc[m][n] = mfma16(af[m][kk], bfv[n][kk], acc[m][n]);
    __syncthreads();
  }

#pragma unroll
  for (int n = 0; n < 4; n++) {
    int col = n0 + wc + n * 16 + lr;
    float bs = bias[col];
#pragma unroll
    for (int m = 0; m < 4; m++) {
      int row0 = m0 + wr + m * 16 + lg * 4;
      if constexpr (EPILOG == 3) {
        if (col >= 2048) {
          // V: write transposed, 4 contiguous rows = one 8B store
          bf16x4 pk;
#pragma unroll
          for (int r = 0; r < 4; r++) pk[r] = (bf16)(acc[m][n][r] + bs);
          *(bf16x4*)(Vout + (size_t)(col - 2048) * 4096 + row0) = pk;
          continue;
        }
      }
#pragma unroll
      for (int r = 0; r < 4; r++) {
        float v = acc[m][n][r] + bs;
        if constexpr (EPILOG == 1) {
          float u = v + 0.044715f * v * v * v;
          float e = __builtin_amdgcn_exp2f(-2.3021144f * u);
          v = v / (1.0f + e);
        }
        if constexpr (EPILOG == 3) { if (col < 1024) v *= QSCALE; }
        Cout[(size_t)(row0 + r) * N + col] = (bf16)v;
      }
    }
  }
}

// ---------------------------------------------------------------------------
// 4-wave GEMM (FFN2): C fp32 [M,N] = A[M,K] @ Bt[N,K]^T + bias. BM=64, BN=128.
// ---------------------------------------------------------------------------
__global__ __launch_bounds__(256) void gemm_ffn2_kernel(
    const bf16* __restrict__ A, const bf16* __restrict__ Bt,
    const float* __restrict__ bias, float* __restrict__ Cout,
    int M, int N, int K) {
  __shared__ bf16 sA[64 * 64];
  __shared__ bf16 sB[128 * 64];
  int nwg = gridDim.x * gridDim.y;
  int bid = blockIdx.y * gridDim.x + blockIdx.x;
  int swz = (bid & 7) * (nwg >> 3) + (bid >> 3);
  int bx = swz % gridDim.x, by = swz / gridDim.x;
  int m0 = by * 64, n0 = bx * 128;
  int tid = threadIdx.x;
  int wave = tid >> 6, lane = tid & 63;
  int lr = lane & 15, lg = lane >> 4;
  int wr = (wave >> 1) * 32, wc = (wave & 1) * 64;

  f32x4 acc[2][4] = {};

  int srow = tid >> 3;
  int scol = (tid & 7) * 8;
  const bf16* Abase = A + (size_t)(m0 + srow) * K + scol;
  const bf16* Bbase = Bt + (size_t)(n0 + srow) * K + scol;

  for (int kt = 0; kt < K; kt += 64) {
#pragma unroll
    for (int i = 0; i < 2; i++)
      gload_lds16(Abase + (size_t)(i * 32) * K + kt,
                  (char*)sA + i * 4096 + wave * 1024);
#pragma unroll
    for (int i = 0; i < 4; i++)
      gload_lds16(Bbase + (size_t)(i * 32) * K + kt,
                  (char*)sB + i * 4096 + wave * 1024);
    __syncthreads();
    bf16x8 af[2][2], bfv[4][2];
#pragma unroll
    for (int m = 0; m < 2; m++)
#pragma unroll
      for (int kk = 0; kk < 2; kk++)
        af[m][kk] = *(const bf16x8*)&sA[(wr + m * 16 + lr) * 64 + kk * 32 + lg * 8];
#pragma unroll
    for (int n = 0; n < 4; n++)
#pragma unroll
      for (int kk = 0; kk < 2; kk++)
        bfv[n][kk] = *(const bf16x8*)&sB[(wc + n * 16 + lr) * 64 + kk * 32 + lg * 8];
#pragma unroll
    for (int kk = 0; kk < 2; kk++)
#pragma unroll
      for (int m = 0; m < 2; m++)
#pragma unroll
        for (int n = 0; n < 4; n++)
          acc[m][n] = mfma16(af[m][kk], bfv[n][kk], acc[m][n]);
    __syncthreads();
  }

#pragma unroll
  for (int n = 0; n < 4; n++) {
    int col = n0 + wc + n * 16 + lr;
    float bs = bias[col];
#pragma unroll
    for (int m = 0; m < 2; m++) {
#pragma unroll
      for (int r = 0; r < 4; r++) {
        int row = m0 + wr + m * 16 + lg * 4 + r;
        Cout[(size_t)row * N + col] = acc[m][n][r] + bs;
      }
    }
  }
}

// ---------------------------------------------------------------------------
// Flash attention, KV-split x2, 32 q rows per wave (QBLK=128 per block).
// grid (32 qtiles, 8 heads, 2 kv-halves), 256 thr, 48KB LDS (3 blocks/CU).
// QK restructured nf-outer: ONE kf read feeds both q-sets (R5 had 2x reads).
// LDS ops/MFMA = 0.69 at R5's occupancy (R6 lesson: occupancy >= ops ratio).
// Static max (m=0, exp2 units); l deferred; unnormalized fp32 O + l partials.
// S^T = K @ Q^T swapped MFMA; P-writes 4x ds_write_b64 per q-set.
// All LDS tiles XOR-swizzled both-sides (rule 21).
// ---------------------------------------------------------------------------
__global__ __launch_bounds__(256) void attn_kernel(
    const bf16* __restrict__ qkv, const bf16* __restrict__ vt,
    float* __restrict__ opart, float* __restrict__ lbuf) {
  constexpr int S = 4096, C3 = 3072;
  __shared__ bf16 sK[64 * 128];       // 16KB
  __shared__ bf16 sV[128 * 64];       // 16KB
  __shared__ bf16 sP[4 * 32 * 64];    // 16KB, 4KB per wave
  int hh = blockIdx.y;
  int q0 = blockIdx.x * 128;
  int z = blockIdx.z;
  int kv_begin = z * (S / 2), kv_end = kv_begin + (S / 2);
  float* obuf = opart + (size_t)z * 4096 * 1024;
  int tid = threadIdx.x, wave = tid >> 6, lane = tid & 63;
  int lr = lane & 15, lg = lane >> 4;

  // Q fragments: 2 sets of 16 q rows (rows q0 + wave*32 + qs*16 + lr)
  bf16x8 qf[2][4];
#pragma unroll
  for (int qs = 0; qs < 2; qs++) {
    const bf16* qrow =
        qkv + (size_t)(q0 + wave * 32 + qs * 16 + lr) * C3 + hh * 128 + lg * 8;
#pragma unroll
    for (int kk = 0; kk < 4; kk++) qf[qs][kk] = *(const bf16x8*)(qrow + kk * 32);
  }
  f32x4 o[2][8] = {};
  float lsum[2] = {0.f, 0.f};

  const int krow_s = tid >> 4;                          // +16*i
  const int kcb = (tid & 15) * 16;
  const int scbK = kcb ^ ((krow_s & 7) << 4);           // i*16 preserves &7
  const int vrow_s = tid >> 3;                          // +32*i
  const int vcb = (tid & 7) * 16;
  const int scbV = vcb ^ ((vrow_s & 7) << 4);

  const bf16* kbase = qkv + 1024 + hh * 128 + scbK / 2;
  const bf16* vbase = vt + (size_t)(hh * 128 + vrow_s) * S + scbV / 2;

  for (int kv0 = kv_begin; kv0 < kv_end; kv0 += 64) {
#pragma unroll
    for (int i = 0; i < 4; i++)
      gload_lds16(kbase + (size_t)(kv0 + i * 16 + krow_s) * C3,
                  (char*)sK + i * 4096 + wave * 1024);
#pragma unroll
    for (int i = 0; i < 4; i++)
      gload_lds16(vbase + (size_t)(i * 32) * S + kv0,
                  (char*)sV + i * 4096 + wave * 1024);
    __syncthreads();

    char* pw = (char*)sP + wave * 4096;

    // QK: S^T = K @ Q^T. nf outer, kk inner; ONE kf read feeds both q-sets.
#pragma unroll
    for (int nf = 0; nf < 4; nf++) {
      f32x4 sc0 = {0.f, 0.f, 0.f, 0.f}, sc1 = sc0;
      __builtin_amdgcn_s_setprio(1);
#pragma unroll
      for (int kk = 0; kk < 4; kk++) {
        int krow = nf * 16 + lr;
        int db = (kk * 64 + lg * 16) ^ ((krow & 7) << 4);
        bf16x8 kf = *(const bf16x8*)((const char*)sK + krow * 256 + db);
        sc0 = mfma16(kf, qf[0][kk], sc0);
        sc1 = mfma16(kf, qf[1][kk], sc1);
      }
      __builtin_amdgcn_s_setprio(0);
      // P = exp2(S); local l accum; write P rows (8B ds_write, swizzled)
      f32x4 scs[2] = {sc0, sc1};
#pragma unroll
      for (int qs = 0; qs < 2; qs++) {
        float p0 = __builtin_amdgcn_exp2f(scs[qs][0]);
        float p1 = __builtin_amdgcn_exp2f(scs[qs][1]);
        float p2 = __builtin_amdgcn_exp2f(scs[qs][2]);
        float p3 = __builtin_amdgcn_exp2f(scs[qs][3]);
        lsum[qs] += (p0 + p1) + (p2 + p3);
        bf16x4 pk;
        pk[0] = (bf16)p0; pk[1] = (bf16)p1; pk[2] = (bf16)p2; pk[3] = (bf16)p3;
        *(bf16x4*)(pw + (qs * 16 + lr) * 128 +
                   ((nf * 32 + lg * 8) ^ ((lr & 7) << 4))) = pk;
      }
    }

    // PV: O[32 q][128 d] += P @ V ; vf reads shared across both q-sets
    bf16x8 pa[2][2];
#pragma unroll
    for (int qs = 0; qs < 2; qs++)
#pragma unroll
      for (int kk = 0; kk < 2; kk++) {
        int db = (kk * 64 + lg * 16) ^ ((lr & 7) << 4);
        pa[qs][kk] = *(const bf16x8*)(pw + (qs * 16 + lr) * 128 + db);
      }
    __builtin_amdgcn_s_setprio(1);
#pragma unroll
    for (int df = 0; df < 8; df++) {
#pragma unroll
      for (int kk = 0; kk < 2; kk++) {
        int vrow = df * 16 + lr;
        int db = (kk * 64 + lg * 16) ^ ((vrow & 7) << 4);
        bf16x8 vf = *(const bf16x8*)((const char*)sV + vrow * 128 + db);
        o[0][df] = mfma16(pa[0][kk], vf, o[0][df]);
        o[1][df] = mfma16(pa[1][kk], vf, o[1][df]);
      }
    }
    __builtin_amdgcn_s_setprio(0);
    __syncthreads();
  }

  // epilogue: finish l partials, write l + unnormalized O
#pragma unroll
  for (int qs = 0; qs < 2; qs++) {
    float ls = lsum[qs];
    ls += __shfl_xor(ls, 16);
    ls += __shfl_xor(ls, 32);   // lane (lr, *) has l-partial for q
    if (lg == 0)
      lbuf[(size_t)(z * 8 + hh) * 4096 + q0 + wave * 32 + qs * 16 + lr] = ls;
#pragma unroll
    for (int df = 0; df < 8; df++) {
      int col = hh * 128 + df * 16 + lr;
#pragma unroll
      for (int r = 0; r < 4; r++) {
        int row = q0 + wave * 32 + qs * 16 + lg * 4 + r;
        obuf[(size_t)row * 1024 + col] = o[qs][df][r];
      }
    }
  }
}

// ---------------------------------------------------------------------------
// Launch. Workspace layout (peak 78.25 MB), liveness-ordered reuse:
//   [0,8M)        h bf16        (ln1 -> resid_ln2)
//   [8,32M)       qkv bf16      (gemmQKV -> attn); after attn:
//     [8,16M)     h2 bf16       (resid_ln2 -> ffn1)
//     [16,24M)    w1T bf16      (transpose -> ffn1)
//     [24,32M)    w2T bf16      (transpose -> ffn2)
//   [32,40M)      vt bf16       (QKV epilogue -> attn)
//   [40,72M)      O0/O1 fp32    (attn -> resid_ln2); then ffn1 bf16 32MB
//   [72,72.25M)   l fp32 [2][8][4096]
//   [72.25,78.25M) qkv_wT bf16 6MB
// ---------------------------------------------------------------------------
extern "C" void kernel_launch(void* const* d_in, const int* in_sizes, int n_in,
                              void* d_out, int out_size, void* d_ws, size_t ws_size,
                              hipStream_t stream) {
  const float* x     = (const float*)d_in[0];
  const float* ln1_g = (const float*)d_in[1];
  const float* ln1_b = (const float*)d_in[2];
  const float* qkv_w = (const float*)d_in[3];
  const float* qkv_b = (const float*)d_in[4];
  const float* ln2_g = (const float*)d_in[5];
  const float* ln2_b = (const float*)d_in[6];
  const float* w1    = (const float*)d_in[7];
  const float* b1    = (const float*)d_in[8];
  const float* w2    = (const float*)d_in[9];
  const float* b2    = (const float*)d_in[10];

  char* ws = (char*)d_ws;
  const size_t MB = 1ull << 20;
  bf16*  h    = (bf16*)(ws + 0);
  bf16*  qkv  = (bf16*)(ws + 8 * MB);
  bf16*  h2   = (bf16*)(ws + 8 * MB);    // alias: qkv dead after attn
  bf16*  w1T  = (bf16*)(ws + 16 * MB);   // alias: qkv dead after attn
  bf16*  w2T  = (bf16*)(ws + 24 * MB);   // alias: qkv dead after attn
  bf16*  vt   = (bf16*)(ws + 32 * MB);
  float* Op   = (float*)(ws + 40 * MB);  // O0 @40M, O1 @56M
  bf16*  ffn1 = (bf16*)(ws + 40 * MB);   // alias: O dead after resid_ln2
  float* lbuf = (float*)(ws + 72 * MB);
  bf16*  wTq  = (bf16*)(ws + 72 * MB + 256 * 1024);
  float* outp = (float*)d_out;

  // 1. LN1
  ln1_kernel<<<4096, 256, 0, stream>>>(x, ln1_g, ln1_b, h);
  // 2. qkv_w [1024,3072] -> wTq [3072,1024]
  transpose_f32_bf16<<<dim3(3072 / 32, 1024 / 32), 256, 0, stream>>>(qkv_w, wTq, 1024, 3072);
  // 3. qkv = h @ qkv_w + b (Q pre-scaled; V written transposed into vt)
  gemm8_kernel<3><<<dim3(3072 / 128, 4096 / 256), 512, 0, stream>>>(
      h, wTq, qkv_b, qkv, vt, 4096, 3072, 1024);
  // 4. attention, KV-split x2, QBLK=128 -> unnormalized fp32 O partials + l
  attn_kernel<<<dim3(32, 8, 2), 256, 0, stream>>>(qkv, vt, Op, lbuf);
  // 5. w1 [1024,4096] -> w1T [4096,1024]   (after attn: overwrites qkv region)
  transpose_f32_bf16<<<dim3(4096 / 32, 1024 / 32), 256, 0, stream>>>(w1, w1T, 1024, 4096);
  // 6. w2 [4096,1024] -> w2T [1024,4096]
  transpose_f32_bf16<<<dim3(1024 / 32, 4096 / 32), 256, 0, stream>>>(w2, w2T, 4096, 1024);
  // 7. h2 = LN2((O0+O1)/l + h)
  resid_ln2_kernel<<<4096, 256, 0, stream>>>(Op, Op + 4096ull * 1024, lbuf, h,
                                             ln2_g, ln2_b, h2);
  // 8. ffn1 = gelu(h2 @ w1 + b1)  [4096,4096] bf16
  gemm8_kernel<1><<<dim3(4096 / 128, 4096 / 256), 512, 0, stream>>>(
      h2, w1T, b1, ffn1, nullptr, 4096, 4096, 1024);
  // 9. out = ffn1 @ w2 + b2  fp32
  gemm_ffn2_kernel<<<dim3(1024 / 128, 4096 / 64), 256, 0, stream>>>(
      ffn1, w2T, b2, outp, 4096, 1024, 4096);
}